// Round 12
// baseline (84.299 us; speedup 1.0000x reference)
//
#include <hip/hip_runtime.h>

// SpatialAttention: B=4 T=12 N=512 D=128, 8 heads x d=16.
// cvt_k (R5) -> qkv_k (LDS-free swapped GEMM) -> attn_k (R5 math, FROZEN;
// Ps retyped u32 + mt-parity dbuf, K direct from global, 35KB LDS) ->
// oproj_k (96-token/256-block).

typedef unsigned short u16;
typedef unsigned int u32;
typedef __bf16 bf16_t;
typedef bf16_t bf16x8 __attribute__((ext_vector_type(8)));
typedef float f32x4 __attribute__((ext_vector_type(4)));
typedef u16 u16x8 __attribute__((ext_vector_type(8)));
typedef u16 u16x4 __attribute__((ext_vector_type(4)));
typedef u32 u32x2 __attribute__((ext_vector_type(2)));
typedef u32 u32x4 __attribute__((ext_vector_type(4)));

__device__ __forceinline__ u16 f2bf(float f) {
    unsigned u = __builtin_bit_cast(unsigned, f);
    u += 0x7FFFu + ((u >> 16) & 1u);   // round-to-nearest-even
    return (u16)(u >> 16);
}

__device__ __forceinline__ f32x4 mfma16(bf16x8 a, bf16x8 b, f32x4 c) {
    return __builtin_amdgcn_mfma_f32_16x16x32_bf16(a, b, c, 0, 0, 0);
}

__device__ __forceinline__ u32 cvt_pk_bf16(float lo, float hi) {
    u32 w;
    asm("v_cvt_pk_bf16_f32 %0, %1, %2" : "=v"(w) : "v"(lo), "v"(hi));
    return w;
}

// ---------------------------------------------------------------------------
// Blocks 0..3071: xc[24576][256] = [bf16(x) | bf16(ste)]  (R5-exact)
// Blocks 3072..3199: weight transpose+convert: wt[3][128][256], wto[2][128][128]
// ---------------------------------------------------------------------------
__global__ __launch_bounds__(256) void cvt_k(const float* __restrict__ x,
                                             const float* __restrict__ ste,
                                             const float* __restrict__ Wq,
                                             const float* __restrict__ Wk,
                                             const float* __restrict__ Wv,
                                             const float* __restrict__ Wo1,
                                             const float* __restrict__ Wo2,
                                             u16* __restrict__ xc,
                                             u16* __restrict__ wtq,
                                             u16* __restrict__ wto1)
{
    const int b = blockIdx.x, tid = threadIdx.x;
    if (b < 3072) {
        long idx = (long)b * 256 + tid;
        long row = idx >> 5; int c = (int)(idx & 31);
        f32x4 a = *(const f32x4*)(x + idx * 4);
        f32x4 s = *(const f32x4*)(ste + idx * 4);
        u16x4 ha, hs;
#pragma unroll
        for (int j = 0; j < 4; ++j) { ha[j] = f2bf(a[j]); hs[j] = f2bf(s[j]); }
        *(u16x4*)(xc + row * 256 + c * 4)       = ha;
        *(u16x4*)(xc + row * 256 + 128 + c * 4) = hs;
    } else {
        int wb = b - 3072;
        const float* src; u16* dst; int K, lb;
        if (wb < 96) { int m = wb >> 5; src = (m == 0) ? Wq : (m == 1) ? Wk : Wv;
                       dst = wtq + m * 32768; K = 256; lb = wb & 31; }
        else         { int m = (wb - 96) >> 4; src = (m == 0) ? Wo1 : Wo2;
                       dst = wto1 + m * 16384; K = 128; lb = (wb - 96) & 15; }
        int pos = lb * 256 + tid;
        f32x4 v = *(const f32x4*)(src + (long)pos * 4);
        int k  = pos >> 5;
        int n0 = (pos * 4) & 127;
#pragma unroll
        for (int j = 0; j < 4; ++j) dst[(n0 + j) * K + k] = f2bf(v[j]);
    }
}

// ---------------------------------------------------------------------------
// LDS-free QKV projection, swapped operands: D[feature][token]. From xc (bf16).
// Grid (192,3): y=0 Q(scaled), y=1 K, y=2 V(V^T out). No LDS, no barriers.
// ---------------------------------------------------------------------------
__global__ __launch_bounds__(256) void qkv_k(const u16* __restrict__ xc,
                                             const u16* __restrict__ wt,
                                             const float* __restrict__ bq,
                                             const float* __restrict__ bk,
                                             const float* __restrict__ bv,
                                             u16* __restrict__ qbuf,
                                             u16* __restrict__ kbuf,
                                             u16* __restrict__ vbuf,
                                             float qscale)
{
    const int y = blockIdx.y;
    const u16* WT     = wt + y * 32768;                 // [128 feat][256 k]
    const float* bias = (y == 0) ? bq : (y == 1) ? bk : bv;
    u16* Out          = (y == 0) ? qbuf : (y == 1) ? kbuf : vbuf;
    const float scale = (y == 0) ? qscale : 1.0f;

    const int tid  = threadIdx.x;
    const int wave = tid >> 6;
    const int lane = tid & 63;
    const int g    = lane >> 4;
    const int lc   = lane & 15;
    const int wr   = wave >> 1;
    const int wc   = wave & 1;
    const long mbase = (long)blockIdx.x * 128;

    const u16* arow = xc + (mbase + wr * 64 + lc) * 256;   // token frags (B operand)
    const u16* brow = WT + (wc * 64 + lc) * 256;           // feature frags (A operand)

    const f32x4 ZERO4 = {0.f, 0.f, 0.f, 0.f};
    f32x4 acc[4][4];
#pragma unroll
    for (int m = 0; m < 4; ++m)
#pragma unroll
        for (int n = 0; n < 4; ++n) acc[m][n] = ZERO4;

#pragma unroll 2
    for (int k0 = 0; k0 < 256; k0 += 32) {
        bf16x8 tf[4], wf[4];
#pragma unroll
        for (int m = 0; m < 4; ++m)
            tf[m] = *(const bf16x8*)(arow + m * 4096 + k0 + g * 8);
#pragma unroll
        for (int n = 0; n < 4; ++n)
            wf[n] = *(const bf16x8*)(brow + n * 4096 + k0 + g * 8);
#pragma unroll
        for (int m = 0; m < 4; ++m)
#pragma unroll
            for (int n = 0; n < 4; ++n)
                acc[m][n] = mfma16(wf[n], tf[m], acc[m][n]);   // D[feat][tok]
    }

#pragma unroll
    for (int m = 0; m < 4; ++m) {
        const long tok = mbase + wr * 64 + m * 16 + lc;
        const long bt = tok >> 9;
        const long nn = tok & 511;
#pragma unroll
        for (int n = 0; n < 4; ++n) {
            const int feat0 = wc * 64 + n * 16 + g * 4;
            const int head  = feat0 >> 4;
            const int d0    = feat0 & 15;
            f32x4 b4 = *(const f32x4*)(bias + feat0);
            if (y == 2) {          // V^T: [head][16][512]
#pragma unroll
                for (int r = 0; r < 4; ++r) {
                    float v = fmaxf(acc[m][n][r] + b4[r], 0.f);
                    Out[((bt * 8 + head) * 16 + d0 + r) * 512 + nn] = f2bf(v);
                }
            } else {               // Q/K: [head][512][16], u16x4 fully coalesced
                u16x4 pk;
#pragma unroll
                for (int r = 0; r < 4; ++r)
                    pk[r] = f2bf(fmaxf(acc[m][n][r] + b4[r], 0.f) * scale);
                *(u16x4*)&Out[((bt * 8 + head) * 512 + nn) * 16 + d0] = pk;
            }
        }
    }
}

// ---------------------------------------------------------------------------
// Flash attention. Math/order identical to the 5/5-validated R5 version.
// Deltas this round (surgical):
//  - Ps retyped: __shared__ u32 (stores u32x2, loads u32x4+bit_cast) so ALL
//    Ps accesses are u32-family — aliasing visible to compiler, no TBAA UB.
//  - Ps double-buffered by mt parity: adjacent mt chains may overlap legally.
//  - K read direct from global (same bytes qkv_k wrote; pure read path).
// LDS 35KB -> 4 blocks/CU. Grid (2,8,48), 4 waves x 64 q-rows.
// ---------------------------------------------------------------------------
__global__ __launch_bounds__(256) void attn_k(const u16* __restrict__ qb,
                                              const u16* __restrict__ kb,
                                              const u16* __restrict__ vtb,
                                              u16* __restrict__ ob)
{
    __shared__ u16 Vt[16][520];          // 16640 B
    __shared__ u32 Ps[4][2][16][36];     // 18432 B; [wave][mt&1][q=lc][u32 key-pair]

    const int tid  = threadIdx.x;
    const int wave = tid >> 6;
    const int lane = tid & 63;
    const int g    = lane >> 4;
    const int lc   = lane & 15;
    const int qt = blockIdx.x, h = blockIdx.y, bt = blockIdx.z;
    const long hb = ((long)(bt * 8 + h)) * 8192;

    const u16x8 ZU8 = {0, 0, 0, 0, 0, 0, 0, 0};
    const bf16x8 zf = __builtin_bit_cast(bf16x8, ZU8);
    const f32x4 ZERO4 = {0.f, 0.f, 0.f, 0.f};

    // stage V^T [16][512]
#pragma unroll
    for (int i = 0; i < 4; ++i) {
        int pos = tid + i * 256;
        int r16 = pos >> 6, c8 = pos & 63;
        *(u16x8*)&Vt[r16][c8 * 8] = *(const u16x8*)(vtb + hb + r16 * 512 + c8 * 8);
    }

    const int qrow0 = qt * 256 + wave * 64;
    bf16x8 qf[4];
#pragma unroll
    for (int mt = 0; mt < 4; ++mt)
        qf[mt] = (g < 2) ? *(const bf16x8*)(qb + hb + (qrow0 + mt * 16 + lc) * 16 + g * 8) : zf;

    // per-lane state for q-row = (mt*16 + lc)
    float m_s[4], l_s[4];
    f32x4 oacc[4];
#pragma unroll
    for (int mt = 0; mt < 4; ++mt) { m_s[mt] = -1e30f; l_s[mt] = 0.f; oacc[mt] = ZERO4; }

    const int bcast = (lane & 48) + ((lane & 48) >> 2);   // src lane base for row g*4+r values

    __syncthreads();   // Vt ready — the only block-wide barrier

    const u16* krow = kb + hb;
    for (int ch = 0; ch < 8; ++ch) {
        bf16x8 kf[4];
#pragma unroll
        for (int nt = 0; nt < 4; ++nt)
            kf[nt] = (g < 2) ? *(const bf16x8*)(krow + (ch * 64 + nt * 16 + lc) * 16 + g * 8) : zf;

#pragma unroll
        for (int mt = 0; mt < 4; ++mt) {
            // S^T tiles: lane (lc,g) holds S[q=lc][key = ch*64 + nt*16 + g*4 + r]
            f32x4 st[4];
#pragma unroll
            for (int nt = 0; nt < 4; ++nt) st[nt] = mfma16(kf[nt], qf[mt], ZERO4);

            float mx = st[0][0];
#pragma unroll
            for (int nt = 0; nt < 4; ++nt)
#pragma unroll
                for (int r = 0; r < 4; ++r) mx = fmaxf(mx, st[nt][r]);
            mx = fmaxf(mx, __shfl_xor(mx, 16));
            mx = fmaxf(mx, __shfl_xor(mx, 32));

            float m0 = m_s[mt];
            if (__any(mx > m0 + 8.f)) {          // rescale path (rare after ch 0)
                float mnew = fmaxf(m0, mx);
                float alpha = __builtin_amdgcn_exp2f(m0 - mnew);
                f32x4 av;
#pragma unroll
                for (int r = 0; r < 4; ++r) av[r] = __shfl(alpha, bcast + r);
                oacc[mt] *= av;
                l_s[mt] *= alpha;
                m_s[mt] = mnew;
            }
            const float mm = m_s[mt];
            float rs = 0.f;
#pragma unroll
            for (int nt = 0; nt < 4; ++nt)
#pragma unroll
                for (int r = 0; r < 4; ++r) {
                    float p = __builtin_amdgcn_exp2f(st[nt][r] - mm);
                    st[nt][r] = p;
                    rs += p;
                }
            rs += __shfl_xor(rs, 16);
            rs += __shfl_xor(rs, 32);
            l_s[mt] += rs;

            // pack P -> Ps[wave][mt&1][q=lc][...] (u32-typed stores; key bf16
            // offset nt*16+g*4 == u32 offset nt*8+g*2)
#pragma unroll
            for (int nt = 0; nt < 4; ++nt) {
                u32x2 w;
                w[0] = cvt_pk_bf16(st[nt][0], st[nt][1]);
                w[1] = cvt_pk_bf16(st[nt][2], st[nt][3]);
                *(u32x2*)&Ps[wave][mt & 1][lc][nt * 8 + g * 2] = w;
            }
            // O += P V  (u32x4 loads from same u32 array -> ordering visible)
#pragma unroll
            for (int ks = 0; ks < 2; ++ks) {
                u32x4 pw = *(const u32x4*)&Ps[wave][mt & 1][lc][ks * 16 + g * 4];
                bf16x8 pf = __builtin_bit_cast(bf16x8, pw);
                bf16x8 vf = *(const bf16x8*)&Vt[lc][ch * 64 + ks * 32 + g * 8];
                oacc[mt] = mfma16(pf, vf, oacc[mt]);
            }
        }
    }

    // write O [24576][128]; l for q-row g*4+r via shfl
#pragma unroll
    for (int mt = 0; mt < 4; ++mt)
#pragma unroll
        for (int r = 0; r < 4; ++r) {
            float lr = __shfl(l_s[mt], bcast + r);
            int row = qrow0 + mt * 16 + g * 4 + r;
            float rl = __builtin_amdgcn_rcpf(lr);
            ob[((long)bt * 512 + row) * 128 + h * 16 + lc] = f2bf(oacc[mt][r] * rl);
        }
}

// ---------------------------------------------------------------------------
// Fused output projections: out = relu(O*Wo1+bo1)*Wo2 + bo2. Swapped operands.
// 96-token tiles, grid 256 (exactly 1 block/CU). acc[3][4], Hs[96][136].
// ---------------------------------------------------------------------------
__global__ __launch_bounds__(256) void oproj_k(const u16* __restrict__ O,
                                               const u16* __restrict__ wt1,
                                               const float* __restrict__ b1,
                                               const u16* __restrict__ wt2,
                                               const float* __restrict__ b2,
                                               float* __restrict__ out)
{
    __shared__ u16 Hs[96][136];   // [token][feature]

    const int tid  = threadIdx.x;
    const int wave = tid >> 6;
    const int lane = tid & 63;
    const int g    = lane >> 4;
    const int lc   = lane & 15;
    const int wr   = wave >> 1;
    const int wc   = wave & 1;
    const long mbase = (long)blockIdx.x * 96;

    const f32x4 ZERO4 = {0.f, 0.f, 0.f, 0.f};
    f32x4 acc[3][4];
#pragma unroll
    for (int m = 0; m < 3; ++m)
#pragma unroll
        for (int n = 0; n < 4; ++n) acc[m][n] = ZERO4;

    const u16* arow  = O   + (mbase + wr * 48 + lc) * 128;   // token frags
    const u16* b1row = wt1 + (wc * 64 + lc) * 128;           // feature frags
    const u16* b2row = wt2 + (wc * 64 + lc) * 128;

    // stage 1: h = relu(O*W1 + b1) -> Hs[tok][feat]
#pragma unroll 2
    for (int k0 = 0; k0 < 128; k0 += 32) {
        bf16x8 tf[3], wf[4];
#pragma unroll
        for (int m = 0; m < 3; ++m)
            tf[m] = *(const bf16x8*)(arow + m * 2048 + k0 + g * 8);
#pragma unroll
        for (int n = 0; n < 4; ++n)
            wf[n] = *(const bf16x8*)(b1row + n * 2048 + k0 + g * 8);
#pragma unroll
        for (int m = 0; m < 3; ++m)
#pragma unroll
            for (int n = 0; n < 4; ++n)
                acc[m][n] = mfma16(wf[n], tf[m], acc[m][n]);
    }
#pragma unroll
    for (int m = 0; m < 3; ++m) {
        const int tok = wr * 48 + m * 16 + lc;
#pragma unroll
        for (int n = 0; n < 4; ++n) {
            const int feat0 = wc * 64 + n * 16 + g * 4;
            f32x4 b4 = *(const f32x4*)(b1 + feat0);
            u16x4 pk;
#pragma unroll
            for (int r = 0; r < 4; ++r)
                pk[r] = f2bf(fmaxf(acc[m][n][r] + b4[r], 0.f));
            *(u16x4*)&Hs[tok][feat0] = pk;
            acc[m][n] = ZERO4;
        }
    }
    __syncthreads();

    // stage 2: out = h*W2 + b2
#pragma unroll 2
    for (int k0 = 0; k0 < 128; k0 += 32) {
        bf16x8 tf[3], wf[4];
#pragma unroll
        for (int m = 0; m < 3; ++m)
            tf[m] = *(const bf16x8*)&Hs[wr * 48 + m * 16 + lc][k0 + g * 8];
#pragma unroll
        for (int n = 0; n < 4; ++n)
            wf[n] = *(const bf16x8*)(b2row + n * 2048 + k0 + g * 8);
#pragma unroll
        for (int m = 0; m < 3; ++m)
#pragma unroll
            for (int n = 0; n < 4; ++n)
                acc[m][n] = mfma16(wf[n], tf[m], acc[m][n]);
    }
#pragma unroll
    for (int m = 0; m < 3; ++m) {
        const long tok = mbase + wr * 48 + m * 16 + lc;
#pragma unroll
        for (int n = 0; n < 4; ++n) {
            const int feat0 = wc * 64 + n * 16 + g * 4;
            f32x4 b4 = *(const f32x4*)(b2 + feat0);
            f32x4 v;
#pragma unroll
            for (int r = 0; r < 4; ++r) v[r] = acc[m][n][r] + b4[r];
            *(f32x4*)&out[tok * 128 + feat0] = v;
        }
    }
}

extern "C" void kernel_launch(void* const* d_in, const int* in_sizes, int n_in,
                              void* d_out, int out_size, void* d_ws, size_t ws_size,
                              hipStream_t stream)
{
    const float* x   = (const float*)d_in[0];
    const float* ste = (const float*)d_in[1];
    const float* Wq  = (const float*)d_in[2];
    const float* bq  = (const float*)d_in[3];
    const float* Wk  = (const float*)d_in[4];
    const float* bk  = (const float*)d_in[5];
    const float* Wv  = (const float*)d_in[6];
    const float* bv  = (const float*)d_in[7];
    const float* Wo1 = (const float*)d_in[8];
    const float* bo1 = (const float*)d_in[9];
    const float* Wo2 = (const float*)d_in[10];
    const float* bo2 = (const float*)d_in[11];
    float* out = (float*)d_out;

    const long MTOT = 24576;
    u16* xc   = (u16*)d_ws;                  // [24576][256] bf16
    u16* qbuf = xc + MTOT * 256;             // [384][512][16]
    u16* kbuf = qbuf + MTOT * 128;
    u16* vbuf = kbuf + MTOT * 128;           // V^T [384][16][512]
    u16* wtq  = vbuf + MTOT * 128;           // W^T bf16: [3][128][256]
    u16* wto1 = wtq + 3 * 32768;             // [2][128][128]
    u16* obuf = xc;                          // reuse xc after QKV

    const float QSCALE = 0.25f * 1.44269504f;   // 1/sqrt(16) * log2(e)

    dim3 blk(256);
    cvt_k<<<dim3(3200), blk, 0, stream>>>(x, ste, Wq, Wk, Wv, Wo1, Wo2, xc, wtq, wto1);
    qkv_k<<<dim3(192, 3), blk, 0, stream>>>(xc, wtq, bq, bk, bv, qbuf, kbuf, vbuf, QSCALE);
    attn_k<<<dim3(2, 8, 48), blk, 0, stream>>>(qbuf, kbuf, vbuf, obuf);
    oproj_k<<<dim3(256), blk, 0, stream>>>(obuf, wto1, bo1, wto1 + 16384, bo2, out);
}